// Round 11
// baseline (932.987 us; speedup 1.0000x reference)
//
#include <hip/hip_runtime.h>
#include <hip/hip_bf16.h>
#include <hip/hip_cooperative_groups.h>

namespace cg = cooperative_groups;

// Problem constants (match reference setup_inputs)
static constexpr int N = 100000;
static constexpr int E = 600000;
static constexpr int D = 128;
static constexpr int B = 10000;
static constexpr int C = 32;
static constexpr int NBc = (N + 1023) / 1024;   // 98 scan chunks per N-array

typedef __attribute__((ext_vector_type(8))) short short8;   // 8 bf16 (4 VGPRs)
typedef __attribute__((ext_vector_type(4))) float f32x4;    // MFMA acc

// bf16 RNE helpers (bit-level, no NaN inputs here)
static __device__ __forceinline__ unsigned short f2bf(float f) {
    unsigned u = __float_as_uint(f);
    unsigned r = (u + 0x7FFFu + ((u >> 16) & 1u)) >> 16;
    return (unsigned short)r;
}
static __device__ __forceinline__ float bf2f(unsigned short h) {
    return __uint_as_float(((unsigned)h) << 16);
}

// split 8 consecutive floats into hi/lo bf16 fragments
static __device__ __forceinline__ void split8(const float4 v0, const float4 v1,
                                              short8& h, short8& l) {
    const float f[8] = {v0.x, v0.y, v0.z, v0.w, v1.x, v1.y, v1.z, v1.w};
    #pragma unroll
    for (int i = 0; i < 8; ++i) {
        unsigned short hh = f2bf(f[i]);
        h[i] = (short)hh;
        l[i] = (short)f2bf(f[i] - bf2f(hh));
    }
}

// ---------------- cooperative preprocessing: CSR + active-set U + weight swizzle ----------------
// Replaces 10 dispatches (memset, deg, 3 scans, fill, mark, 2 scans, uscan, swz)
// with one kernel using grid.sync() phase barriers.
// flag semantics: bit1 (2) = label node, bit0 (1) = in-neighbor of a label.
// U = {flag != 0}.  deg total over all dst == E by construction.
__global__ __launch_bounds__(256) void prep_k(
    const int* __restrict__ src, const int* __restrict__ dst,
    const int* __restrict__ label_pos,
    const float* __restrict__ W1l, const float* __restrict__ W1r,
    const float* __restrict__ W2l, const float* __restrict__ W2r,
    int* __restrict__ deg, int* __restrict__ flag,
    int* __restrict__ roff, int* __restrict__ cur, int* __restrict__ csr_src,
    int* __restrict__ map, int* __restrict__ ulist,
    int* __restrict__ bsum, int* __restrict__ boff, int* __restrict__ ucnt,
    unsigned short* __restrict__ Wsw)
{
    cg::grid_group grid = cg::this_grid();
    __shared__ int lsum[256];
    const int t = threadIdx.x;
    const int gtid = blockIdx.x * 256 + t;
    const int gsz = gridDim.x * 256;

    // ---- phase 0: zero deg/flag; swizzle weights into MFMA-B fragment order
    for (int i = gtid; i < N; i += gsz) { deg[i] = 0; flag[i] = 0; }
    for (int f4 = gtid; f4 < 4 * 16384; f4 += gsz) {
        const int m = f4 >> 14;
        const int f = f4 & 16383;
        const float* W = (m == 0) ? W1l : (m == 1) ? W1r : (m == 2) ? W2l : W2r;
        unsigned short* o = Wsw + (size_t)m * 32768;
        int j = f & 7;
        int lane = (f >> 3) & 63;
        int fi = f >> 9;                                 // ko*8+no
        int k = (fi >> 3) * 32 + (lane >> 4) * 8 + j;
        int n = (fi & 7) * 16 + (lane & 15);
        float a = W[k * 128 + n];
        unsigned short h = f2bf(a);
        o[f] = h;
        o[16384 + f] = f2bf(a - bf2f(h));
    }
    grid.sync();

    // ---- phase 1: mark labels
    for (int i = gtid; i < B; i += gsz) flag[label_pos[i]] = 2;
    grid.sync();

    // ---- phase 2: degree count + neighbor U-mark (edge pass)
    for (int e = gtid; e < E; e += gsz) {
        int d = dst[e];
        atomicAdd(&deg[d], 1);
        if (flag[d] >= 2) atomicOr(&flag[src[e]], 1);
    }
    grid.sync();

    // ---- phase 3: chunk sums: chunks [0,NBc) over deg, [NBc,2NBc) over (flag!=0)
    for (int c = blockIdx.x; c < 2 * NBc; c += gridDim.x) {
        const bool isdeg = c < NBc;
        const int base = (isdeg ? c : c - NBc) * 1024 + t * 4;
        int s = 0;
        #pragma unroll
        for (int i = 0; i < 4; ++i) {
            int idx = base + i;
            if (idx < N) s += isdeg ? deg[idx] : (flag[idx] != 0 ? 1 : 0);
        }
        lsum[t] = s;
        __syncthreads();
        for (int off = 128; off > 0; off >>= 1) {
            if (t < off) lsum[t] += lsum[t + off];
            __syncthreads();
        }
        if (t == 0) bsum[c] = lsum[0];
        __syncthreads();   // WAR protection on lsum across chunk iterations
    }
    grid.sync();

    // ---- phase 4: block 0 scans the 2*NBc chunk sums
    if (blockIdx.x == 0) {
        const int v = (t < 2 * NBc) ? bsum[t] : 0;
        lsum[t] = v;
        __syncthreads();
        for (int off = 1; off < 256; off <<= 1) {
            int u = (t >= off) ? lsum[t - off] : 0;
            __syncthreads();
            lsum[t] += u;
            __syncthreads();
        }
        if (t < 2 * NBc) boff[t] = lsum[t] - v;         // exclusive
        if (t == 0) roff[N] = E;                        // deg total == E
        if (t == 2 * NBc - 1) *ucnt = lsum[t] - E;      // flag total
    }
    grid.sync();

    // ---- phase 5: chunked re-scan -> roff/cur (deg) and map/ulist (flag)
    for (int c = blockIdx.x; c < 2 * NBc; c += gridDim.x) {
        const bool isdeg = c < NBc;
        const int base = (isdeg ? c : c - NBc) * 1024 + t * 4;
        int d[4];
        int s = 0;
        #pragma unroll
        for (int i = 0; i < 4; ++i) {
            int idx = base + i;
            d[i] = (idx < N) ? (isdeg ? deg[idx] : (flag[idx] != 0 ? 1 : 0)) : 0;
            s += d[i];
        }
        lsum[t] = s;
        __syncthreads();
        for (int off = 1; off < 256; off <<= 1) {
            int u = (t >= off) ? lsum[t - off] : 0;
            __syncthreads();
            lsum[t] += u;
            __syncthreads();
        }
        int run = boff[c] + lsum[t] - s;
        if (!isdeg) run -= E;   // flag prefixes sit after the deg total
        #pragma unroll
        for (int i = 0; i < 4; ++i) {
            int idx = base + i;
            if (idx < N) {
                if (isdeg) {
                    roff[idx] = run;
                    cur[idx]  = run;
                    run += d[i];
                } else if (d[i]) {
                    map[idx] = run;
                    ulist[run] = idx;
                    ++run;
                }
            }
        }
        __syncthreads();
    }
    grid.sync();

    // ---- phase 6: CSR fill
    for (int e = gtid; e < E; e += gsz) {
        int p = atomicAdd(&cur[dst[e]], 1);
        csr_src[p] = src[e];
    }
}

// ---------------- gather-mean aggregation (r9 v1: measured best) ----------------
// one wave per output row w: node = rows[w]; sources optionally mapped.
template <bool GATHER, bool MAP>
__global__ __launch_bounds__(256) void gather_mean_k(
    const float* __restrict__ x, const int* __restrict__ roff,
    const int* __restrict__ csr_src, const int* __restrict__ rows,
    const int* __restrict__ map, const int* __restrict__ nrows_ptr,
    float* __restrict__ out, int nrows_max) {
    const int nrows = nrows_ptr ? nrows_ptr[0] : nrows_max;
    const int w = blockIdx.x * (blockDim.x >> 6) + (threadIdx.x >> 6);
    if (w >= nrows) return;
    const int lane = threadIdx.x & 63;
    const int n  = GATHER ? rows[w] : w;
    const int jb = roff[n];
    const int je = roff[n + 1];
    const float* xb = x + lane * 2;

    float ax = 0.f, ay = 0.f;
    int j = jb;
    for (; j + 4 <= je; j += 4) {
        int s0 = csr_src[j + 0];
        int s1 = csr_src[j + 1];
        int s2 = csr_src[j + 2];
        int s3 = csr_src[j + 3];
        if (MAP) { s0 = map[s0]; s1 = map[s1]; s2 = map[s2]; s3 = map[s3]; }
        float2 v0 = *reinterpret_cast<const float2*>(xb + (size_t)s0 * D);
        float2 v1 = *reinterpret_cast<const float2*>(xb + (size_t)s1 * D);
        float2 v2 = *reinterpret_cast<const float2*>(xb + (size_t)s2 * D);
        float2 v3 = *reinterpret_cast<const float2*>(xb + (size_t)s3 * D);
        ax += v0.x + v1.x + v2.x + v3.x;
        ay += v0.y + v1.y + v2.y + v3.y;
    }
    for (; j < je; ++j) {
        int s = csr_src[j];
        if (MAP) s = map[s];
        float2 v = *reinterpret_cast<const float2*>(xb + (size_t)s * D);
        ax += v.x;
        ay += v.y;
    }
    const float inv = 1.0f / fmaxf((float)(je - jb), 1.0f);
    *reinterpret_cast<float2*>(out + (size_t)w * D + lane * 2) =
        make_float2(ax * inv, ay * inv);
}

// ---------------- SAGE layer, split-bf16 MFMA, LDS-free / barrier-free ----------------
// xout[r] = relu( mean[r]@Wl + bl + xsrc[g(r)]@Wr ),  g(r) = map?[rows?[r]]
// A@W ~= Ah@Wh + Al@Wh + Ah@Wl  (3-term hi/lo split, residual ~2^-18)
// 64-row blocks: 4 waves, each owns 16 rows x 128 cols.
template <bool GATHER, bool MAP>
__global__ __launch_bounds__(256, 4) void sage_mfma_k(
    const float* __restrict__ mean, const float* __restrict__ xsrc,
    const int* __restrict__ rows, const int* __restrict__ map,
    const int* __restrict__ nrows_ptr,
    const unsigned short* __restrict__ WlSw, const unsigned short* __restrict__ WrSw,
    const float* __restrict__ bl, float* __restrict__ xout, int nrows_max)
{
    const int nrows = nrows_ptr ? nrows_ptr[0] : nrows_max;
    const int rb = blockIdx.x * 64;
    if (rb >= nrows) return;

    const int t = threadIdx.x;
    const int w = t >> 6;
    const int lane = t & 63;
    const int mcol = lane & 15;
    const int q = lane >> 4;
    const int r = rb + w * 16 + mcol;   // this wave's A-fragment row

    f32x4 acc[8];
    #pragma unroll
    for (int no = 0; no < 8; ++no) acc[no] = (f32x4){0.f, 0.f, 0.f, 0.f};

    // resolve branch-1 source row once
    size_t gidx = 0;
    if (r < nrows) {
        int g = GATHER ? rows[r] : r;
        if (MAP) g = map[g];
        gidx = (size_t)g;
    }

    #pragma unroll
    for (int br = 0; br < 2; ++br) {
        const unsigned short* __restrict__ Wm = br ? WrSw : WlSw;
        #pragma unroll
        for (int kp = 0; kp < 4; ++kp) {
            // ---- A fragment: global -> regs, split hi/lo
            short8 aH, aL;
            {
                float4 v0 = make_float4(0.f, 0.f, 0.f, 0.f);
                float4 v1 = make_float4(0.f, 0.f, 0.f, 0.f);
                if (r < nrows) {
                    const float* p = (br == 0)
                        ? mean + (size_t)r * D + kp * 32 + q * 8
                        : xsrc + gidx * D + kp * 32 + q * 8;
                    v0 = *reinterpret_cast<const float4*>(p);
                    v1 = *reinterpret_cast<const float4*>(p + 4);
                }
                split8(v0, v1, aH, aL);
            }
            // ---- MFMA over 8 col-tiles; B straight from L2 in fragment order
            #pragma unroll
            for (int no = 0; no < 8; ++no) {
                const size_t fo = ((size_t)(kp * 8 + no) * 64 + lane) * 8;
                short8 bh = *reinterpret_cast<const short8*>(Wm + fo);
                short8 bo = *reinterpret_cast<const short8*>(Wm + 16384 + fo);
                acc[no] = __builtin_amdgcn_mfma_f32_16x16x32_bf16(aH, bh, acc[no], 0, 0, 0);
                acc[no] = __builtin_amdgcn_mfma_f32_16x16x32_bf16(aL, bh, acc[no], 0, 0, 0);
                acc[no] = __builtin_amdgcn_mfma_f32_16x16x32_bf16(aH, bo, acc[no], 0, 0, 0);
            }
        }
    }

    // ---- epilogue: bias + relu + store (C/D layout: col=lane&15, row=q*4+reg)
    #pragma unroll
    for (int no = 0; no < 8; ++no) {
        const int col = no * 16 + mcol;
        const float bias = bl[col];
        #pragma unroll
        for (int ri = 0; ri < 4; ++ri) {
            const int row = rb + w * 16 + q * 4 + ri;
            if (row < nrows)
                xout[(size_t)row * D + col] = fmaxf(acc[no][ri] + bias, 0.f);
        }
    }
}

// ---------------- classifier: out = relu(x2g@Wc1+bc1) @ Wc2 + bc2 ----------------
__global__ __launch_bounds__(256) void classifier_k(
    const float* __restrict__ x2g,
    const float* __restrict__ Wc1, const float* __restrict__ bc1,
    const float* __restrict__ Wc2, const float* __restrict__ bc2,
    float* __restrict__ out, int nrows) {
    __shared__ float Xs[32][128];
    __shared__ float Hs[32][128];
    const int rb = blockIdx.x * 32;
    const int t  = threadIdx.x;

    #pragma unroll
    for (int it = 0; it < 4; ++it) {
        int j  = t + it * 256;
        int r  = j >> 5;
        int k4 = j & 31;
        int row = rb + r;
        float4 v = make_float4(0.f, 0.f, 0.f, 0.f);
        if (row < nrows) v = *reinterpret_cast<const float4*>(x2g + (size_t)row * D + k4 * 4);
        *reinterpret_cast<float4*>(&Xs[r][k4 * 4]) = v;
    }
    __syncthreads();

    {
        const int col  = t & 127;
        const int half = t >> 7;
        float acc[16];
        const float bias = bc1[col];
        #pragma unroll
        for (int i = 0; i < 16; ++i) acc[i] = bias;
        for (int k = 0; k < 128; ++k) {
            float w = Wc1[k * 128 + col];
            #pragma unroll
            for (int i = 0; i < 16; ++i)
                acc[i] = fmaf(Xs[half * 16 + i][k], w, acc[i]);
        }
        #pragma unroll
        for (int i = 0; i < 16; ++i)
            Hs[half * 16 + i][col] = fmaxf(acc[i], 0.0f);
    }
    __syncthreads();

    {
        const int c  = t & 31;
        const int rg = t >> 5;
        float o[4];
        const float b2 = bc2[c];
        #pragma unroll
        for (int i = 0; i < 4; ++i) o[i] = b2;
        for (int k = 0; k < 128; ++k) {
            float w = Wc2[k * 32 + c];
            #pragma unroll
            for (int i = 0; i < 4; ++i)
                o[i] = fmaf(Hs[rg + 8 * i][k], w, o[i]);
        }
        #pragma unroll
        for (int i = 0; i < 4; ++i) {
            int row = rb + rg + 8 * i;
            if (row < nrows) out[(size_t)row * C + c] = o[i];
        }
    }
}

// ---------------- launch ----------------

extern "C" void kernel_launch(void* const* d_in, const int* in_sizes, int n_in,
                              void* d_out, int out_size, void* d_ws, size_t ws_size,
                              hipStream_t stream) {
    const float* node_state = (const float*)d_in[0];
    const int*   edge_index = (const int*)d_in[1];
    const int*   label_pos  = (const int*)d_in[2];
    const float* W1l = (const float*)d_in[3];
    const float* b1l = (const float*)d_in[4];
    const float* W1r = (const float*)d_in[5];
    const float* W2l = (const float*)d_in[6];
    const float* b2l = (const float*)d_in[7];
    const float* W2r = (const float*)d_in[8];
    const float* Wc1 = (const float*)d_in[9];
    const float* bc1 = (const float*)d_in[10];
    const float* Wc2 = (const float*)d_in[11];
    const float* bc2 = (const float*)d_in[12];
    float* out = (float*)d_out;

    const int* src = edge_index;       // edge_index[0]
    const int* dst = edge_index + E;   // edge_index[1]

    // workspace layout (floats first for alignment; identical footprint to r9)
    char* ws = (char*)d_ws;
    float* x1c   = (float*)ws;                    ws += sizeof(float) * (size_t)N * D;
    float* bufA  = (float*)ws;                    ws += sizeof(float) * (size_t)N * D;
    unsigned short* Wsw = (unsigned short*)ws;    ws += sizeof(unsigned short) * 4 * 32768;
    int* deg     = (int*)ws;                      ws += sizeof(int) * N;
    int* flag    = (int*)ws;                      ws += sizeof(int) * N;
    int* roff    = (int*)ws;                      ws += sizeof(int) * (N + 1);
    int* cur     = (int*)ws;                      ws += sizeof(int) * N;
    int* csr_src = (int*)ws;                      ws += sizeof(int) * E;
    int* map     = (int*)ws;                      ws += sizeof(int) * N;
    int* ulist   = (int*)ws;                      ws += sizeof(int) * N;
    int* bsum    = (int*)ws;                      ws += sizeof(int) * 256;
    int* boff    = (int*)ws;                      ws += sizeof(int) * 256;
    int* ucnt    = (int*)ws;                      ws += sizeof(int);
    // bufA: mean1c [ucnt][D]; then mean2g [B][D] + x2g [B][D]
    float* mean1c = bufA;
    float* mean2g = bufA;
    float* x2g    = bufA + (size_t)B * D;

    const int TB = 256;

    // ---- cooperative preprocessing: one dispatch for CSR + U + swizzle ----
    {
        void* args[] = {
            (void*)&src, (void*)&dst, (void*)&label_pos,
            (void*)&W1l, (void*)&W1r, (void*)&W2l, (void*)&W2r,
            (void*)&deg, (void*)&flag, (void*)&roff, (void*)&cur, (void*)&csr_src,
            (void*)&map, (void*)&ulist, (void*)&bsum, (void*)&boff, (void*)&ucnt,
            (void*)&Wsw
        };
        hipLaunchCooperativeKernel((const void*)prep_k, dim3(1024), dim3(256),
                                   args, 0, stream);
    }

    // ---- layer 1: only U rows (compact outputs) ----
    gather_mean_k<true, false><<<(N + 3) / 4, TB, 0, stream>>>(
        node_state, roff, csr_src, ulist, nullptr, ucnt, mean1c, N);
    sage_mfma_k<true, false><<<(N + 63) / 64, TB, 0, stream>>>(
        mean1c, node_state, ulist, nullptr, ucnt,
        Wsw, Wsw + 32768, b1l, x1c, N);

    // ---- layer 2: label rows; sources resolved through map into compact x1c ----
    gather_mean_k<true, true><<<(B + 3) / 4, TB, 0, stream>>>(
        x1c, roff, csr_src, label_pos, map, nullptr, mean2g, B);
    sage_mfma_k<true, true><<<(B + 63) / 64, TB, 0, stream>>>(
        mean2g, x1c, label_pos, map, nullptr,
        Wsw + 65536, Wsw + 98304, b2l, x2g, B);

    // ---- classifier ----
    classifier_k<<<(B + 31) / 32, TB, 0, stream>>>(x2g, Wc1, bc1, Wc2, bc2, out, B);
}

// Round 12
// 286.478 us; speedup vs baseline: 3.2567x; 3.2567x over previous
//
#include <hip/hip_runtime.h>
#include <hip/hip_bf16.h>

// Problem constants (match reference setup_inputs)
static constexpr int N = 100000;
static constexpr int E = 600000;
static constexpr int D = 128;
static constexpr int B = 10000;
static constexpr int C = 32;

typedef __attribute__((ext_vector_type(8))) short short8;   // 8 bf16 (4 VGPRs)
typedef __attribute__((ext_vector_type(4))) float f32x4;    // MFMA acc

// bf16 RNE helpers (bit-level, no NaN inputs here)
static __device__ __forceinline__ unsigned short f2bf(float f) {
    unsigned u = __float_as_uint(f);
    unsigned r = (u + 0x7FFFu + ((u >> 16) & 1u)) >> 16;
    return (unsigned short)r;
}
static __device__ __forceinline__ float bf2f(unsigned short h) {
    return __uint_as_float(((unsigned)h) << 16);
}

// split 8 consecutive floats into hi/lo bf16 fragments
static __device__ __forceinline__ void split8(const float4 v0, const float4 v1,
                                              short8& h, short8& l) {
    const float f[8] = {v0.x, v0.y, v0.z, v0.w, v1.x, v1.y, v1.z, v1.w};
    #pragma unroll
    for (int i = 0; i < 8; ++i) {
        unsigned short hh = f2bf(f[i]);
        h[i] = (short)hh;
        l[i] = (short)f2bf(f[i] - bf2f(hh));
    }
}

// ---------------- CSR build ----------------

__global__ void deg_k(const int* __restrict__ dst, int* __restrict__ deg, int nE) {
    int i = blockIdx.x * blockDim.x + threadIdx.x;
    if (i < nE) atomicAdd(&deg[dst[i]], 1);
}

// per-block (1024 elems) sums of an int array
__global__ __launch_bounds__(256) void scan1_k(const int* __restrict__ v,
                                               int* __restrict__ bsum, int n) {
    __shared__ int lsum[256];
    const int t = threadIdx.x;
    const int base = blockIdx.x * 1024 + t * 4;
    int s = 0;
    #pragma unroll
    for (int i = 0; i < 4; ++i) {
        int idx = base + i;
        if (idx < n) s += v[idx];
    }
    lsum[t] = s;
    __syncthreads();
    for (int off = 128; off > 0; off >>= 1) {
        if (t < off) lsum[t] += lsum[t + off];
        __syncthreads();
    }
    if (t == 0) bsum[blockIdx.x] = lsum[0];
}

// single tiny block scans <=128 block sums; writes *total
__global__ __launch_bounds__(128) void scan2_k(const int* __restrict__ bsum,
                                               int* __restrict__ boff,
                                               int* __restrict__ total, int nb) {
    __shared__ int s[128];
    const int t = threadIdx.x;
    const int v = (t < nb) ? bsum[t] : 0;
    s[t] = v;
    __syncthreads();
    for (int off = 1; off < 128; off <<= 1) {
        int u = (t >= off) ? s[t - off] : 0;
        __syncthreads();
        s[t] += u;
        __syncthreads();
    }
    if (t < nb) boff[t] = s[t] - v;
    if (t == 127) *total = s[127];
}

// CSR phase 3: write roff & cur from deg + block offsets
__global__ __launch_bounds__(256) void scan3_k(const int* __restrict__ deg,
                                               const int* __restrict__ boff,
                                               int* __restrict__ roff,
                                               int* __restrict__ cur, int n) {
    __shared__ int lsum[256];
    const int t = threadIdx.x;
    const int base = blockIdx.x * 1024 + t * 4;
    int d[4];
    int s = 0;
    #pragma unroll
    for (int i = 0; i < 4; ++i) {
        int idx = base + i;
        d[i] = (idx < n) ? deg[idx] : 0;
        s += d[i];
    }
    lsum[t] = s;
    __syncthreads();
    for (int off = 1; off < 256; off <<= 1) {
        int u = (t >= off) ? lsum[t - off] : 0;
        __syncthreads();
        lsum[t] += u;
        __syncthreads();
    }
    int run = boff[blockIdx.x] + lsum[t] - s;
    #pragma unroll
    for (int i = 0; i < 4; ++i) {
        int idx = base + i;
        if (idx < n) {
            roff[idx] = run;
            cur[idx]  = run;
            run += d[i];
        }
    }
}

__global__ void fill_k(const int* __restrict__ src, const int* __restrict__ dst,
                       int* __restrict__ cur, int* __restrict__ csr_src, int nE) {
    int e = blockIdx.x * blockDim.x + threadIdx.x;
    if (e < nE) {
        int p = atomicAdd(&cur[dst[e]], 1);
        csr_src[p] = src[e];
    }
}

// ---------------- active-set (U) build ----------------
// U = label_pos  ∪  {in-neighbors of label_pos}; flag[] marked by wave-per-label
__global__ __launch_bounds__(256) void mark_k(
    const int* __restrict__ label_pos, const int* __restrict__ roff,
    const int* __restrict__ csr_src, int* __restrict__ flag, int nlab) {
    const int w = blockIdx.x * (blockDim.x >> 6) + (threadIdx.x >> 6);
    if (w >= nlab) return;
    const int lane = threadIdx.x & 63;
    const int v = label_pos[w];
    if (lane == 0) flag[v] = 1;
    const int jb = roff[v], je = roff[v + 1];
    for (int j = jb + lane; j < je; j += 64) flag[csr_src[j]] = 1;
}

// compaction: for flagged idx, map[idx]=pos, ulist[pos]=idx
__global__ __launch_bounds__(256) void uscan3_k(const int* __restrict__ flag,
                                                const int* __restrict__ boff,
                                                int* __restrict__ map,
                                                int* __restrict__ ulist, int n) {
    __shared__ int lsum[256];
    const int t = threadIdx.x;
    const int base = blockIdx.x * 1024 + t * 4;
    int f[4];
    int s = 0;
    #pragma unroll
    for (int i = 0; i < 4; ++i) {
        int idx = base + i;
        f[i] = (idx < n) ? flag[idx] : 0;
        s += f[i];
    }
    lsum[t] = s;
    __syncthreads();
    for (int off = 1; off < 256; off <<= 1) {
        int u = (t >= off) ? lsum[t - off] : 0;
        __syncthreads();
        lsum[t] += u;
        __syncthreads();
    }
    int run = boff[blockIdx.x] + lsum[t] - s;
    #pragma unroll
    for (int i = 0; i < 4; ++i) {
        int idx = base + i;
        if (idx < n && f[i]) {
            map[idx] = run;
            ulist[run] = idx;
            ++run;
        }
    }
}

// ---------------- weight swizzle: fp32 W[128][128] -> MFMA-B fragment order, hi/lo bf16 ----------------
// 64 blocks: 16 chunks per matrix. out[plane][((ko*8+no)*64+lane)*8+j] =
//   W[ko*32+(lane>>4)*8+j][no*16+(lane&15)]
__global__ __launch_bounds__(256) void swz_k(const float* W0, const float* W1,
                                             const float* W2, const float* W3,
                                             unsigned short* __restrict__ out) {
    const int m = blockIdx.x >> 4;
    const int chunk = blockIdx.x & 15;
    const float* W = (m == 0) ? W0 : (m == 1) ? W1 : (m == 2) ? W2 : W3;
    unsigned short* o = out + (size_t)m * 32768;
    #pragma unroll
    for (int it = 0; it < 4; ++it) {
        int f = chunk * 1024 + it * 256 + threadIdx.x;   // 0..16383
        int j = f & 7;
        int lane = (f >> 3) & 63;
        int fi = f >> 9;                                 // ko*8+no
        int k = (fi >> 3) * 32 + (lane >> 4) * 8 + j;
        int n = (fi & 7) * 16 + (lane & 15);
        float a = W[k * 128 + n];
        unsigned short h = f2bf(a);
        unsigned short l = f2bf(a - bf2f(h));
        o[f] = h;
        o[16384 + f] = l;
    }
}

// ---------------- gather-mean aggregation (r9 v1: measured best) ----------------
// one wave per output row w: node = rows[w]; sources optionally mapped.
template <bool GATHER, bool MAP>
__global__ __launch_bounds__(256) void gather_mean_k(
    const float* __restrict__ x, const int* __restrict__ roff,
    const int* __restrict__ csr_src, const int* __restrict__ rows,
    const int* __restrict__ map, const int* __restrict__ nrows_ptr,
    float* __restrict__ out, int nrows_max) {
    const int nrows = nrows_ptr ? nrows_ptr[0] : nrows_max;
    const int w = blockIdx.x * (blockDim.x >> 6) + (threadIdx.x >> 6);
    if (w >= nrows) return;
    const int lane = threadIdx.x & 63;
    const int n  = GATHER ? rows[w] : w;
    const int jb = roff[n];
    const int je = roff[n + 1];
    const float* xb = x + lane * 2;

    float ax = 0.f, ay = 0.f;
    int j = jb;
    for (; j + 4 <= je; j += 4) {
        int s0 = csr_src[j + 0];
        int s1 = csr_src[j + 1];
        int s2 = csr_src[j + 2];
        int s3 = csr_src[j + 3];
        if (MAP) { s0 = map[s0]; s1 = map[s1]; s2 = map[s2]; s3 = map[s3]; }
        float2 v0 = *reinterpret_cast<const float2*>(xb + (size_t)s0 * D);
        float2 v1 = *reinterpret_cast<const float2*>(xb + (size_t)s1 * D);
        float2 v2 = *reinterpret_cast<const float2*>(xb + (size_t)s2 * D);
        float2 v3 = *reinterpret_cast<const float2*>(xb + (size_t)s3 * D);
        ax += v0.x + v1.x + v2.x + v3.x;
        ay += v0.y + v1.y + v2.y + v3.y;
    }
    for (; j < je; ++j) {
        int s = csr_src[j];
        if (MAP) s = map[s];
        float2 v = *reinterpret_cast<const float2*>(xb + (size_t)s * D);
        ax += v.x;
        ay += v.y;
    }
    const float inv = 1.0f / fmaxf((float)(je - jb), 1.0f);
    *reinterpret_cast<float2*>(out + (size_t)w * D + lane * 2) =
        make_float2(ax * inv, ay * inv);
}

// ---------------- SAGE layer, split-bf16 MFMA, LDS-free / barrier-free ----------------
// xout[r] = relu( mean[r]@Wl + bl + xsrc[g(r)]@Wr ),  g(r) = map?[rows?[r]]
// A@W ~= Ah@Wh + Al@Wh + Ah@Wl  (3-term hi/lo split, residual ~2^-18)
// 32-row blocks, 4 waves = {row-half} x {col-half}; each wave 16 rows x 64 cols,
// acc[4]. Doubles the grid vs the 64-row version (r9 was grid-limited at
// ~3 blocks/CU, Occupancy 15.5%).
template <bool GATHER, bool MAP>
__global__ __launch_bounds__(256, 6) void sage_mfma_k(
    const float* __restrict__ mean, const float* __restrict__ xsrc,
    const int* __restrict__ rows, const int* __restrict__ map,
    const int* __restrict__ nrows_ptr,
    const unsigned short* __restrict__ WlSw, const unsigned short* __restrict__ WrSw,
    const float* __restrict__ bl, float* __restrict__ xout, int nrows_max)
{
    const int nrows = nrows_ptr ? nrows_ptr[0] : nrows_max;
    const int rb = blockIdx.x * 32;
    if (rb >= nrows) return;

    const int t = threadIdx.x;
    const int wrow = (t >> 6) & 1;      // row half of the block's 32 rows
    const int wcol = t >> 7;            // col half (0: cols 0-63, 1: 64-127)
    const int lane = t & 63;
    const int mcol = lane & 15;
    const int q = lane >> 4;
    const int r = rb + wrow * 16 + mcol;   // this wave's A-fragment row

    f32x4 acc[4];
    #pragma unroll
    for (int no = 0; no < 4; ++no) acc[no] = (f32x4){0.f, 0.f, 0.f, 0.f};

    // resolve branch-1 source row once
    size_t gidx = 0;
    if (r < nrows) {
        int g = GATHER ? rows[r] : r;
        if (MAP) g = map[g];
        gidx = (size_t)g;
    }

    #pragma unroll
    for (int br = 0; br < 2; ++br) {
        const unsigned short* __restrict__ Wm = br ? WrSw : WlSw;
        #pragma unroll
        for (int kp = 0; kp < 4; ++kp) {
            // ---- A fragment: global -> regs, split hi/lo
            short8 aH, aL;
            {
                float4 v0 = make_float4(0.f, 0.f, 0.f, 0.f);
                float4 v1 = make_float4(0.f, 0.f, 0.f, 0.f);
                if (r < nrows) {
                    const float* p = (br == 0)
                        ? mean + (size_t)r * D + kp * 32 + q * 8
                        : xsrc + gidx * D + kp * 32 + q * 8;
                    v0 = *reinterpret_cast<const float4*>(p);
                    v1 = *reinterpret_cast<const float4*>(p + 4);
                }
                split8(v0, v1, aH, aL);
            }
            // ---- MFMA over this wave's 4 col-tiles; B from L2 in fragment order
            #pragma unroll
            for (int no = 0; no < 4; ++no) {
                const size_t fo = ((size_t)(kp * 8 + wcol * 4 + no) * 64 + lane) * 8;
                short8 bh = *reinterpret_cast<const short8*>(Wm + fo);
                short8 bo = *reinterpret_cast<const short8*>(Wm + 16384 + fo);
                acc[no] = __builtin_amdgcn_mfma_f32_16x16x32_bf16(aH, bh, acc[no], 0, 0, 0);
                acc[no] = __builtin_amdgcn_mfma_f32_16x16x32_bf16(aL, bh, acc[no], 0, 0, 0);
                acc[no] = __builtin_amdgcn_mfma_f32_16x16x32_bf16(aH, bo, acc[no], 0, 0, 0);
            }
        }
    }

    // ---- epilogue: bias + relu + store (C/D layout: col=lane&15, row=q*4+reg)
    #pragma unroll
    for (int no = 0; no < 4; ++no) {
        const int col = wcol * 64 + no * 16 + mcol;
        const float bias = bl[col];
        #pragma unroll
        for (int ri = 0; ri < 4; ++ri) {
            const int row = rb + wrow * 16 + q * 4 + ri;
            if (row < nrows)
                xout[(size_t)row * D + col] = fmaxf(acc[no][ri] + bias, 0.f);
        }
    }
}

// ---------------- classifier: out = relu(x2g@Wc1+bc1) @ Wc2 + bc2 ----------------
__global__ __launch_bounds__(256) void classifier_k(
    const float* __restrict__ x2g,
    const float* __restrict__ Wc1, const float* __restrict__ bc1,
    const float* __restrict__ Wc2, const float* __restrict__ bc2,
    float* __restrict__ out, int nrows) {
    __shared__ float Xs[32][128];
    __shared__ float Hs[32][128];
    const int rb = blockIdx.x * 32;
    const int t  = threadIdx.x;

    #pragma unroll
    for (int it = 0; it < 4; ++it) {
        int j  = t + it * 256;
        int r  = j >> 5;
        int k4 = j & 31;
        int row = rb + r;
        float4 v = make_float4(0.f, 0.f, 0.f, 0.f);
        if (row < nrows) v = *reinterpret_cast<const float4*>(x2g + (size_t)row * D + k4 * 4);
        *reinterpret_cast<float4*>(&Xs[r][k4 * 4]) = v;
    }
    __syncthreads();

    {
        const int col  = t & 127;
        const int half = t >> 7;
        float acc[16];
        const float bias = bc1[col];
        #pragma unroll
        for (int i = 0; i < 16; ++i) acc[i] = bias;
        for (int k = 0; k < 128; ++k) {
            float w = Wc1[k * 128 + col];
            #pragma unroll
            for (int i = 0; i < 16; ++i)
                acc[i] = fmaf(Xs[half * 16 + i][k], w, acc[i]);
        }
        #pragma unroll
        for (int i = 0; i < 16; ++i)
            Hs[half * 16 + i][col] = fmaxf(acc[i], 0.0f);
    }
    __syncthreads();

    {
        const int c  = t & 31;
        const int rg = t >> 5;
        float o[4];
        const float b2 = bc2[c];
        #pragma unroll
        for (int i = 0; i < 4; ++i) o[i] = b2;
        for (int k = 0; k < 128; ++k) {
            float w = Wc2[k * 32 + c];
            #pragma unroll
            for (int i = 0; i < 4; ++i)
                o[i] = fmaf(Hs[rg + 8 * i][k], w, o[i]);
        }
        #pragma unroll
        for (int i = 0; i < 4; ++i) {
            int row = rb + rg + 8 * i;
            if (row < nrows) out[(size_t)row * C + c] = o[i];
        }
    }
}

// ---------------- launch ----------------

extern "C" void kernel_launch(void* const* d_in, const int* in_sizes, int n_in,
                              void* d_out, int out_size, void* d_ws, size_t ws_size,
                              hipStream_t stream) {
    const float* node_state = (const float*)d_in[0];
    const int*   edge_index = (const int*)d_in[1];
    const int*   label_pos  = (const int*)d_in[2];
    const float* W1l = (const float*)d_in[3];
    const float* b1l = (const float*)d_in[4];
    const float* W1r = (const float*)d_in[5];
    const float* W2l = (const float*)d_in[6];
    const float* b2l = (const float*)d_in[7];
    const float* W2r = (const float*)d_in[8];
    const float* Wc1 = (const float*)d_in[9];
    const float* bc1 = (const float*)d_in[10];
    const float* Wc2 = (const float*)d_in[11];
    const float* bc2 = (const float*)d_in[12];
    float* out = (float*)d_out;

    const int* src = edge_index;       // edge_index[0]
    const int* dst = edge_index + E;   // edge_index[1]

    // workspace layout (floats first for alignment)
    char* ws = (char*)d_ws;
    float* x1c   = (float*)ws;                    ws += sizeof(float) * (size_t)N * D;
    float* bufA  = (float*)ws;                    ws += sizeof(float) * (size_t)N * D;
    unsigned short* Wsw = (unsigned short*)ws;    ws += sizeof(unsigned short) * 4 * 32768;
    int* deg     = (int*)ws;                      ws += sizeof(int) * N;
    int* flag    = (int*)ws;                      ws += sizeof(int) * N;  // adjacent to deg: one memset
    int* roff    = (int*)ws;                      ws += sizeof(int) * (N + 1);
    int* cur     = (int*)ws;                      ws += sizeof(int) * N;
    int* csr_src = (int*)ws;                      ws += sizeof(int) * E;
    int* map     = (int*)ws;                      ws += sizeof(int) * N;
    int* ulist   = (int*)ws;                      ws += sizeof(int) * N;
    int* bsum    = (int*)ws;                      ws += sizeof(int) * 128;
    int* boff    = (int*)ws;                      ws += sizeof(int) * 128;
    int* ucnt    = (int*)ws;                      ws += sizeof(int);
    // bufA: mean1c [cnt][D]; then mean2g [B][D] + x2g [B][D]
    float* mean1c = bufA;
    float* mean2g = bufA;
    float* x2g    = bufA + (size_t)B * D;

    const int TB = 256;
    const int NB = (N + 1023) / 1024;   // 98 scan blocks

    // ---- CSR build (deg+flag zeroed in ONE memset; they're adjacent) ----
    hipMemsetAsync(deg, 0, sizeof(int) * 2 * N, stream);
    deg_k<<<(E + TB - 1) / TB, TB, 0, stream>>>(dst, deg, E);
    scan1_k<<<NB, 256, 0, stream>>>(deg, bsum, N);
    scan2_k<<<1, 128, 0, stream>>>(bsum, boff, roff + N, NB);
    scan3_k<<<NB, 256, 0, stream>>>(deg, boff, roff, cur, N);
    fill_k<<<(E + TB - 1) / TB, TB, 0, stream>>>(src, dst, cur, csr_src, E);

    // ---- active-set U = labels ∪ in-neighbors(labels) ----
    mark_k<<<(B + 3) / 4, TB, 0, stream>>>(label_pos, roff, csr_src, flag, B);
    scan1_k<<<NB, 256, 0, stream>>>(flag, bsum, N);
    scan2_k<<<1, 128, 0, stream>>>(bsum, boff, ucnt, NB);
    uscan3_k<<<NB, 256, 0, stream>>>(flag, boff, map, ulist, N);

    // ---- weight swizzle (W1l, W1r, W2l, W2r), 64-way parallel ----
    swz_k<<<64, 256, 0, stream>>>(W1l, W1r, W2l, W2r, Wsw);

    // ---- layer 1: only U rows (compact outputs) ----
    gather_mean_k<true, false><<<(N + 3) / 4, TB, 0, stream>>>(
        node_state, roff, csr_src, ulist, nullptr, ucnt, mean1c, N);
    sage_mfma_k<true, false><<<(N + 31) / 32, TB, 0, stream>>>(
        mean1c, node_state, ulist, nullptr, ucnt,
        Wsw, Wsw + 32768, b1l, x1c, N);

    // ---- layer 2: label rows; sources resolved through map into compact x1c ----
    gather_mean_k<true, true><<<(B + 3) / 4, TB, 0, stream>>>(
        x1c, roff, csr_src, label_pos, map, nullptr, mean2g, B);
    sage_mfma_k<true, true><<<(B + 31) / 32, TB, 0, stream>>>(
        mean2g, x1c, label_pos, map, nullptr,
        Wsw + 65536, Wsw + 98304, b2l, x2g, B);

    // ---- classifier ----
    classifier_k<<<(B + 31) / 32, TB, 0, stream>>>(x2g, Wc1, bc1, Wc2, bc2, out, B);
}